// Round 17
// baseline (445.821 us; speedup 1.0000x reference)
//
#include <hip/hip_runtime.h>
#include <math.h>

#define FEAT 256
#define NHEAD 8
#define HD 32
#define NLAYERS 3
#define EHR_IN 498
#define MAXLEN 500
#define BATCH 16
#define CXR_IN 2048
#define FFDIM 1024
#define NROWS 32
#define TLEN 501

#define F_GELU 1
#define F_RESID 2
#define F_POSEMB 4
#define F_POS0 8

typedef __bf16 bf16x8 __attribute__((ext_vector_type(8)));
typedef __bf16 bf16x4 __attribute__((ext_vector_type(4)));
typedef float f32x4 __attribute__((ext_vector_type(4)));

// ---------------------------------------------------------------------------
// Weight prep: fp32 W[K][N] -> bf16 W^T[N][Kpad] (zero-padded K).
// ---------------------------------------------------------------------------
struct WDesc { const float* src; unsigned dstOff; int K, N, Kpad; };
struct WPack { WDesc d[13]; };

__global__ __launch_bounds__(256) void wconv_kernel(WPack p, __bf16* __restrict__ wb)
{
    WDesc w = p.d[blockIdx.z];
    int n0 = blockIdx.x * 32, k0 = blockIdx.y * 32;
    if (n0 >= w.N || k0 >= w.Kpad) return;
    __shared__ float t[32][33];
    int tid = threadIdx.x;
    int c = tid & 31, r = tid >> 5;
#pragma unroll
    for (int i = 0; i < 4; ++i) {
        int k = k0 + r + i * 8;
        int n = n0 + c;
        t[r + i * 8][c] = (k < w.K && n < w.N) ? w.src[(long long)k * w.N + n] : 0.f;
    }
    __syncthreads();
    int nl = tid >> 3, kq = (tid & 7) * 4;
    int n = n0 + nl;
    if (n < w.N) {
        bf16x4 v;
#pragma unroll
        for (int j = 0; j < 4; ++j) v[j] = (__bf16)t[kq + j][nl];
        *(bf16x4*)(wb + w.dstOff + (long long)n * w.Kpad + k0 + kq) = v;
    }
}

// ---------------------------------------------------------------------------
// bf16 MFMA GEMM, BK=64, double-buffered LDS (validated r12: 445 us).
// Padded LDS rows (72 bf16 = 144 B) keep bank spread; do NOT replace with
// unpadded+XOR (r15 lesson: 16B-chunk swizzle can't fix stride%128B==0).
// ABF: 1 = A bf16, 0 = A fp32. CBF: 0 fp32 / 1 bf16 / 2 both.
// ---------------------------------------------------------------------------
template<int ABF, int CBF>
__global__ __launch_bounds__(256) void gemm_mfma(
    const void* __restrict__ Av, int lda, long long aStrideZ, int Mrows,
    const __bf16* __restrict__ WT, int kpad, int K,
    void* __restrict__ Cv, void* __restrict__ Cv2, int ldc, long long cStrideZ,
    const float* __restrict__ bias,
    const float* __restrict__ resid, long long resStrideZ,
    const float* __restrict__ modv, const float* __restrict__ posm,
    const int* __restrict__ seqlen, int lenMode, int flags)
{
    int z = blockIdx.z;
    int len = (lenMode == 2) ? Mrows
            : (lenMode == 0) ? seqlen[z]
            : ((z & 1) ? 1 : seqlen[z >> 1]);
    int m0 = blockIdx.x * 64;
    if (m0 >= len) return;
    int n0 = blockIdx.y * 64;

    __shared__ __bf16 As[2][64][72];
    __shared__ __bf16 Bs[2][64][72];

    int tid = threadIdx.x;
    int wave = tid >> 6, lane = tid & 63;
    int wm = wave >> 1, wn = wave & 1;
    int fm = lane & 15, kgrp = lane >> 4;

    f32x4 acc[2][2];
#pragma unroll
    for (int i = 0; i < 2; ++i)
#pragma unroll
        for (int j = 0; j < 2; ++j)
#pragma unroll
            for (int r = 0; r < 4; ++r) acc[i][j][r] = 0.f;

    int srow = tid >> 2;          // 0..63
    int skq  = (tid & 3) * 16;    // 0/16/32/48
    int garow = m0 + srow;
    bool rowok = garow < Mrows;

    int nk = (K + 63) >> 6;
    bf16x8 a0, a1, b0, b1;

    auto loadAB = [&](int kt) {
        int k0 = kt << 6;
        if (ABF) {
            if (rowok) {
                const __bf16* ap = (const __bf16*)Av + (long long)z * aStrideZ
                                 + (long long)garow * lda + k0 + skq;
                a0 = *(const bf16x8*)ap;
                a1 = *(const bf16x8*)(ap + 8);
            } else {
#pragma unroll
                for (int j = 0; j < 8; ++j) { a0[j] = (__bf16)0.f; a1[j] = (__bf16)0.f; }
            }
        } else {
            const float* ap = (const float*)Av + (long long)z * aStrideZ
                            + (long long)garow * lda + k0 + skq;
            float va[16];
            if (rowok && k0 + skq + 15 < K) {
#pragma unroll
                for (int j = 0; j < 16; j += 2) {
                    float2 t = *(const float2*)(ap + j);
                    va[j] = t.x; va[j + 1] = t.y;
                }
            } else {
#pragma unroll
                for (int j = 0; j < 16; ++j)
                    va[j] = (rowok && k0 + skq + j < K) ? ap[j] : 0.f;
            }
#pragma unroll
            for (int j = 0; j < 8; ++j) {
                a0[j] = (__bf16)va[j];
                a1[j] = (__bf16)va[j + 8];
            }
        }
        const __bf16* wp = WT + (long long)(n0 + srow) * kpad + k0 + skq;
        b0 = *(const bf16x8*)wp;
        b1 = *(const bf16x8*)(wp + 8);
    };

    auto writeAB = [&](int buf) {
        *(bf16x8*)&As[buf][srow][skq]     = a0;
        *(bf16x8*)&As[buf][srow][skq + 8] = a1;
        *(bf16x8*)&Bs[buf][srow][skq]     = b0;
        *(bf16x8*)&Bs[buf][srow][skq + 8] = b1;
    };

    loadAB(0);
    writeAB(0);
    __syncthreads();

    for (int kt = 0; kt < nk; ++kt) {
        int cur = kt & 1;
        bool more = (kt + 1 < nk);
        if (more) loadAB(kt + 1);    // global loads in flight during MFMAs
#pragma unroll
        for (int kk2 = 0; kk2 < 2; ++kk2) {
            bf16x8 bfr[2];
#pragma unroll
            for (int j = 0; j < 2; ++j)
                bfr[j] = *(const bf16x8*)&Bs[cur][wn * 32 + j * 16 + fm][kk2 * 32 + kgrp * 8];
#pragma unroll
            for (int i = 0; i < 2; ++i) {
                bf16x8 af = *(const bf16x8*)&As[cur][wm * 32 + i * 16 + fm][kk2 * 32 + kgrp * 8];
#pragma unroll
                for (int j = 0; j < 2; ++j)
                    acc[i][j] = __builtin_amdgcn_mfma_f32_16x16x32_bf16(af, bfr[j], acc[i][j], 0, 0, 0);
            }
        }
        if (more) writeAB(cur ^ 1);
        __syncthreads();
    }

    int rbase = (lane >> 4) * 4;
    int ccol = lane & 15;
#pragma unroll
    for (int i = 0; i < 2; ++i) {
#pragma unroll
        for (int r = 0; r < 4; ++r) {
            int gm = m0 + wm * 32 + i * 16 + rbase + r;
            if (gm >= len) continue;
#pragma unroll
            for (int j = 0; j < 2; ++j) {
                int gn = n0 + wn * 32 + j * 16 + ccol;
                float v = acc[i][j][r] + bias[gn];
                if (flags & F_POSEMB) v += modv[gn] + posm[(long long)gm * FEAT + gn];
                if (flags & F_POS0)   v += modv[gn] + posm[gn];
                if (flags & F_RESID)  v += resid[(long long)z * resStrideZ + (long long)gm * ldc + gn];
                if (flags & F_GELU)   v = 0.5f * v * (1.f + erff(v * 0.70710678118654752f));
                long long cidx = (long long)z * cStrideZ + (long long)gm * ldc + gn;
                if (CBF == 1) ((__bf16*)Cv)[cidx] = (__bf16)v;
                else          ((float*)Cv)[cidx] = v;
                if (CBF == 2) ((__bf16*)Cv2)[cidx] = (__bf16)v;
            }
        }
    }
}

// ---------------------------------------------------------------------------
// CXR projection, K-split 2-pass fp32 (validated round 7).
// ---------------------------------------------------------------------------
__global__ __launch_bounds__(256) void cxr_part(
    const float* __restrict__ cxr, const float* __restrict__ W,
    float* __restrict__ part)
{
    int b = blockIdx.x, ks = blockIdx.y;
    int n = threadIdx.x;
    __shared__ float a[128];
    int k0 = ks * 128;
    if (n < 128) a[n] = cxr[(long long)b * CXR_IN + k0 + n];
    __syncthreads();
    float acc0 = 0.f, acc1 = 0.f, acc2 = 0.f, acc3 = 0.f;
    const float* wp = W + (long long)k0 * FEAT + n;
#pragma unroll 8
    for (int k = 0; k < 128; k += 4) {
        acc0 += a[k]     * wp[(long long)k * FEAT];
        acc1 += a[k + 1] * wp[(long long)(k + 1) * FEAT];
        acc2 += a[k + 2] * wp[(long long)(k + 2) * FEAT];
        acc3 += a[k + 3] * wp[(long long)(k + 3) * FEAT];
    }
    part[((long long)b * 16 + ks) * FEAT + n] = acc0 + acc1 + acc2 + acc3;
}

__global__ __launch_bounds__(256) void cxr_fin(
    const float* __restrict__ part, const float* __restrict__ bias,
    const float* __restrict__ mod1, const float* __restrict__ pos0,
    float* __restrict__ x, __bf16* __restrict__ xb)
{
    int b = blockIdx.x;
    int n = threadIdx.x;
    float s = 0.f;
#pragma unroll
    for (int ks = 0; ks < 16; ++ks)
        s += part[((long long)b * 16 + ks) * FEAT + n];
    float v = s + bias[n] + mod1[n] + pos0[n];
    long long idx = ((long long)(2 * b + 1) * TLEN) * FEAT + n;
    x[idx] = v;
    xb[idx] = (__bf16)v;
}

// ---------------------------------------------------------------------------
// MFMA flash attention, q-tile 128, 8 waves (512 threads); validated r11.
// ---------------------------------------------------------------------------
__global__ __launch_bounds__(512) void attn_mfma(
    const __bf16* __restrict__ qkv, __bf16* __restrict__ o,
    const int* __restrict__ seqlen)
{
    int n = blockIdx.z, h = blockIdx.y, qt = blockIdx.x;
    int len = (n & 1) ? 1 : seqlen[n >> 1];
    int q0 = qt * 128;
    if (q0 >= len) return;

    int tid = threadIdx.x;
    int wave = tid >> 6, lane = tid & 63;
    int fr = lane & 15, kg = lane >> 4;

    const __bf16* base = qkv + (long long)n * TLEN * 768;
    const float scale = 0.17677669529663687f;

    int qrow = q0 + wave * 16 + fr;
    if (qrow >= len) qrow = len - 1;
    bf16x8 qfrag = *(const bf16x8*)(base + (long long)qrow * 768 + h * HD + kg * 8);

    f32x4 po0 = {0.f, 0.f, 0.f, 0.f}, po1 = {0.f, 0.f, 0.f, 0.f};
    float m = -3.0e38f, l = 0.f;

    __shared__ bf16x8 stage[2][544];

    int t2 = tid & 255;
    int f_    = t2 >> 6;
    int kgrp_ = (t2 >> 4) & 3;
    int mm_   = t2 & 15;
    int kKeyL  = ((mm_ >> 2) << 3) + ((f_ & 1) << 2) + (mm_ & 3) + ((f_ >> 1) << 5);
    int kChunk = (f_ * 4 + kgrp_) * 17 + mm_;
    int vDim   = ((f_ & 1) << 4) + mm_;
    int vKeyB  = ((f_ >> 1) << 5) + (kgrp_ << 3);
    int vChunk = 272 + (f_ * 4 + kgrp_) * 17 + mm_;

    int nt = (len + 63) >> 6;

    auto do_stage = [&](int t, int buf) {
        int k0 = t << 6;
        if (tid < 256) {
            bf16x8 kv;
            int key = k0 + kKeyL;
            if (key < len) {
                kv = *(const bf16x8*)(base + (long long)key * 768 + 256 + h * HD + kgrp_ * 8);
            } else {
#pragma unroll
                for (int j = 0; j < 8; ++j) kv[j] = (__bf16)0.f;
            }
            stage[buf][kChunk] = kv;
        } else {
            bf16x8 vv;
#pragma unroll
            for (int j = 0; j < 8; ++j) {
                int vkey = k0 + vKeyB + j;
                vv[j] = (vkey < len) ? base[(long long)vkey * 768 + 512 + h * HD + vDim]
                                     : (__bf16)0.f;
            }
            stage[buf][vChunk] = vv;
        }
    };

    do_stage(0, 0);
    __syncthreads();

    for (int t = 0; t < nt; ++t) {
        int buf = t & 1;
        if (t + 1 < nt) do_stage(t + 1, buf ^ 1);

        int k0 = t << 6;
        bf16x8 kf0 = stage[buf][(0 * 4 + kg) * 17 + fr];
        bf16x8 kf1 = stage[buf][(1 * 4 + kg) * 17 + fr];
        bf16x8 kf2 = stage[buf][(2 * 4 + kg) * 17 + fr];
        bf16x8 kf3 = stage[buf][(3 * 4 + kg) * 17 + fr];

        f32x4 zero = {0.f, 0.f, 0.f, 0.f};
        f32x4 s0 = __builtin_amdgcn_mfma_f32_16x16x32_bf16(kf0, qfrag, zero, 0, 0, 0);
        f32x4 s1 = __builtin_amdgcn_mfma_f32_16x16x32_bf16(kf1, qfrag, zero, 0, 0, 0);
        f32x4 s2 = __builtin_amdgcn_mfma_f32_16x16x32_bf16(kf2, qfrag, zero, 0, 0, 0);
        f32x4 s3 = __builtin_amdgcn_mfma_f32_16x16x32_bf16(kf3, qfrag, zero, 0, 0, 0);

        float sc[16];
        int kb = k0 + kg * 8;
#pragma unroll
        for (int r = 0; r < 4; ++r) {
            sc[r]      = (kb + r < len)      ? s0[r] * scale : -3.0e38f;
            sc[4 + r]  = (kb + 4 + r < len)  ? s1[r] * scale : -3.0e38f;
            sc[8 + r]  = (kb + 32 + r < len) ? s2[r] * scale : -3.0e38f;
            sc[12 + r] = (kb + 36 + r < len) ? s3[r] * scale : -3.0e38f;
        }
        float tm = sc[0];
#pragma unroll
        for (int i = 1; i < 16; ++i) tm = fmaxf(tm, sc[i]);
        tm = fmaxf(tm, __shfl_xor(tm, 16));
        tm = fmaxf(tm, __shfl_xor(tm, 32));
        float mn = fmaxf(m, tm);
        float corr = __expf(m - mn);
        l *= corr;
#pragma unroll
        for (int r = 0; r < 4; ++r) { po0[r] *= corr; po1[r] *= corr; }
        m = mn;

        float p[16];
        float lsum = 0.f;
#pragma unroll
        for (int i = 0; i < 16; ++i) { p[i] = __expf(sc[i] - m); lsum += p[i]; }
        lsum += __shfl_xor(lsum, 16);
        lsum += __shfl_xor(lsum, 32);
        l += lsum;

        bf16x8 pf0, pf1;
#pragma unroll
        for (int j = 0; j < 8; ++j) { pf0[j] = (__bf16)p[j]; pf1[j] = (__bf16)p[8 + j]; }

        bf16x8 vf00 = stage[buf][272 + (0 * 4 + kg) * 17 + fr];
        bf16x8 vf01 = stage[buf][272 + (1 * 4 + kg) * 17 + fr];
        bf16x8 vf10 = stage[buf][272 + (2 * 4 + kg) * 17 + fr];
        bf16x8 vf11 = stage[buf][272 + (3 * 4 + kg) * 17 + fr];

        po0 = __builtin_amdgcn_mfma_f32_16x16x32_bf16(vf00, pf0, po0, 0, 0, 0);
        po0 = __builtin_amdgcn_mfma_f32_16x16x32_bf16(vf10, pf1, po0, 0, 0, 0);
        po1 = __builtin_amdgcn_mfma_f32_16x16x32_bf16(vf01, pf0, po1, 0, 0, 0);
        po1 = __builtin_amdgcn_mfma_f32_16x16x32_bf16(vf11, pf1, po1, 0, 0, 0);

        __syncthreads();
    }

    int q = q0 + wave * 16 + fr;
    if (q < len) {
        float inv = 1.f / l;
        __bf16* orow = o + ((long long)n * TLEN + q) * FEAT + h * HD;
        bf16x4 w0, w1;
#pragma unroll
        for (int r = 0; r < 4; ++r) {
            w0[r] = (__bf16)(po0[r] * inv);
            w1[r] = (__bf16)(po1[r] * inv);
        }
        *(bf16x4*)(orow + kg * 4) = w0;
        *(bf16x4*)(orow + 16 + kg * 4) = w1;
    }
}

// ---------------------------------------------------------------------------
// LayerNorm over last dim (256). 256-thread blocks = 4 waves, one wave per
// row. Writes fp32 x AND bf16 xb. (Validated r16.)
// ---------------------------------------------------------------------------
__global__ __launch_bounds__(256) void ln_kernel(
    const float* __restrict__ tmp, float* __restrict__ x, __bf16* __restrict__ xb,
    const float* __restrict__ g, const float* __restrict__ b,
    const int* __restrict__ seqlen)
{
    int n = blockIdx.y;
    int len = (n & 1) ? 1 : seqlen[n >> 1];
    int t = blockIdx.x * 4 + (threadIdx.x >> 6);
    if (t >= len) return;
    int tid = threadIdx.x & 63;
    const float* row = tmp + ((long long)n * TLEN + t) * FEAT;
    int f = tid * 4;
    float4 v = *(const float4*)(row + f);
    float s = v.x + v.y + v.z + v.w;
#pragma unroll
    for (int off = 32; off; off >>= 1) s += __shfl_down(s, off);
    float mu = __shfl(s, 0) * (1.f / 256.f);
    float dx = v.x - mu, dy = v.y - mu, dz = v.z - mu, dw = v.w - mu;
    float q = dx * dx + dy * dy + dz * dz + dw * dw;
#pragma unroll
    for (int off = 32; off; off >>= 1) q += __shfl_down(q, off);
    float var = __shfl(q, 0) * (1.f / 256.f);
    float r = rsqrtf(var + 1e-5f);
    float4 ov;
    ov.x = dx * r * g[f + 0] + b[f + 0];
    ov.y = dy * r * g[f + 1] + b[f + 1];
    ov.z = dz * r * g[f + 2] + b[f + 2];
    ov.w = dw * r * g[f + 3] + b[f + 3];
    long long idx = ((long long)n * TLEN + t) * FEAT + f;
    *(float4*)(x + idx) = ov;
    bf16x4 bv;
    bv[0] = (__bf16)ov.x; bv[1] = (__bf16)ov.y;
    bv[2] = (__bf16)ov.z; bv[3] = (__bf16)ov.w;
    *(bf16x4*)(xb + idx) = bv;
}

// ---------------------------------------------------------------------------
// Fused final-LN2 + masked mean-pool + output projection.
//   pooled[f] = g[f]/cnt * Σ_t (tmp[t,f]-mu_t)*rs_t + b[f]   (cnt>0)
// Phase 1: wave-per-token two-pass stats (identical math to ln_kernel).
// Phase 2: scaled token-sum. Phase 3: projection (x2 outputs).
// ---------------------------------------------------------------------------
__global__ __launch_bounds__(1024) void pool_ln_kernel(
    const float* __restrict__ tmp,
    const float* __restrict__ g, const float* __restrict__ b,
    const float* __restrict__ W, const float* __restrict__ ob,
    const int* __restrict__ seqlen, const int* __restrict__ valid_cxr,
    float* __restrict__ out)
{
    int n = blockIdx.x;
    int tid = threadIdx.x;
    int cnt = (n & 1) ? (valid_cxr[n >> 1] != 0 ? 1 : 0) : seqlen[n >> 1];

    __shared__ float musig[TLEN + 3][2];
    __shared__ float part[4][FEAT];
    __shared__ float pooled[FEAT];

    const float* base = tmp + (long long)n * TLEN * FEAT;

    // ---- phase 1: per-token stats; wave w -> tokens w, w+16, ... ----
    int wv = tid >> 6, lanei = tid & 63;
    for (int t = wv; t < cnt; t += 16) {
        const float* row = base + (long long)t * FEAT;
        float4 v = *(const float4*)(row + lanei * 4);
        float s = v.x + v.y + v.z + v.w;
#pragma unroll
        for (int off = 32; off; off >>= 1) s += __shfl_down(s, off);
        float mu = __shfl(s, 0) * (1.f / 256.f);
        float dx = v.x - mu, dy = v.y - mu, dz = v.z - mu, dw = v.w - mu;
        float q = dx * dx + dy * dy + dz * dz + dw * dw;
#pragma unroll
        for (int off = 32; off; off >>= 1) q += __shfl_down(q, off);
        if (lanei == 0) {
            float var = __shfl(q, 0) * (1.f / 256.f);
            musig[t][0] = mu;
            musig[t][1] = rsqrtf(var + 1e-5f);
        }
    }
    __syncthreads();

    // ---- phase 2: scaled token sum ----
    int f = tid & 255, tg = tid >> 8;
    float s0 = 0.f;
    for (int t = tg; t < cnt; t += 4) {
        float mu = musig[t][0], rs = musig[t][1];
        s0 += (base[(long long)t * FEAT + f] - mu) * rs;
    }
    part[tg][f] = s0;
    __syncthreads();
    if (tg == 0) {
        float v = part[0][f] + part[1][f] + part[2][f] + part[3][f];
        pooled[f] = cnt ? (g[f] * v / (float)cnt + b[f]) : 0.f;
    }
    __syncthreads();

    // ---- phase 3: projection ----
    float acc = 0.f;
    const float* wcol = W + f;
#pragma unroll 8
    for (int k = tg * 64; k < tg * 64 + 64; ++k)
        acc += pooled[k] * wcol[(long long)k * FEAT];
    __syncthreads();
    part[tg][f] = acc;
    __syncthreads();
    if (tg == 0) {
        float v = part[0][f] + part[1][f] + part[2][f] + part[3][f] + ob[f];
        out[(long long)n * FEAT + f] = v;
        out[NROWS * FEAT + (long long)n * FEAT + f] = v;
    }
}

// ---------------------------------------------------------------------------
extern "C" void kernel_launch(void* const* d_in, const int* in_sizes, int n_in,
                              void* d_out, int out_size, void* d_ws, size_t ws_size,
                              hipStream_t stream)
{
    const float* ehr_data = (const float*)d_in[0];
    const float* cxr_data = (const float*)d_in[1];
    const int*   seqlen   = (const int*)d_in[2];
    const int*   valid_cxr = (const int*)d_in[3];
    const float* ehr_w = (const float*)d_in[4];
    const float* ehr_b = (const float*)d_in[5];
    const float* cxr_w = (const float*)d_in[6];
    const float* cxr_b = (const float*)d_in[7];
    const float* modemb = (const float*)d_in[8];
    const float* pos    = (const float*)d_in[9];
    const float* qkv_w  = (const float*)d_in[10];
    const float* qkv_b  = (const float*)d_in[11];
    const float* aow    = (const float*)d_in[12];
    const float* aob    = (const float*)d_in[13];
    const float* ln1g   = (const float*)d_in[14];
    const float* ln1b   = (const float*)d_in[15];
    const float* ln2g   = (const float*)d_in[16];
    const float* ln2b   = (const float*)d_in[17];
    const float* ff1w   = (const float*)d_in[18];
    const float* ff1b   = (const float*)d_in[19];
    const float* ff2w   = (const float*)d_in[20];
    const float* ff2b   = (const float*)d_in[21];
    const float* outw   = (const float*)d_in[22];
    const float* outb   = (const float*)d_in[23];
    float* out = (float*)d_out;

    // ---- workspace layout (float slots) ----
    float* ws    = (float*)d_ws;
    float* x     = ws;
    __bf16* xb   = (__bf16*)(ws + 4104192);
    __bf16* qkv  = (__bf16*)(ws + 6156288);
    __bf16* obuf = (__bf16*)(ws + 12312576);
    __bf16* h    = (__bf16*)(ws + 6156288);
    float* tmp   = ws + 14364672;
    __bf16* wb   = (__bf16*)(ws + 18468864);
    float* cpart = ws + 19714048;

    WPack p;
    unsigned off = 0;
    p.d[0] = { ehr_w, off, EHR_IN, FEAT, 512 };            off += 256 * 512;
    unsigned qkvOff = off;
    for (int l = 0; l < 3; ++l) { p.d[1 + l] = { qkv_w + (long long)l * FEAT * 768, off, FEAT, 768, FEAT };  off += 768 * FEAT; }
    unsigned aoOff = off;
    for (int l = 0; l < 3; ++l) { p.d[4 + l] = { aow + (long long)l * FEAT * FEAT, off, FEAT, FEAT, FEAT };  off += FEAT * FEAT; }
    unsigned ff1Off = off;
    for (int l = 0; l < 3; ++l) { p.d[7 + l] = { ff1w + (long long)l * FEAT * FFDIM, off, FEAT, FFDIM, FEAT }; off += FFDIM * FEAT; }
    unsigned ff2Off = off;
    for (int l = 0; l < 3; ++l) { p.d[10 + l] = { ff2w + (long long)l * FFDIM * FEAT, off, FFDIM, FEAT, FFDIM }; off += FEAT * FFDIM; }

    wconv_kernel<<<dim3(32, 32, 13), 256, 0, stream>>>(p, wb);

    // ehr projection -> even rows of x (+ bf16 mirror xb)
    gemm_mfma<0, 2><<<dim3(8, 4, 16), 256, 0, stream>>>(
        ehr_data, EHR_IN, (long long)MAXLEN * EHR_IN, MAXLEN,
        wb + 0, 512, EHR_IN,
        x, xb, FEAT, (long long)2 * TLEN * FEAT,
        ehr_b, nullptr, 0, modemb, pos, seqlen, 0, F_POSEMB);
    // cxr projection -> odd rows token 0 (+ xb)
    cxr_part<<<dim3(BATCH, 16), 256, 0, stream>>>(cxr_data, cxr_w, cpart);
    cxr_fin<<<BATCH, 256, 0, stream>>>(cpart, cxr_b, modemb + FEAT, pos, x, xb);

    for (int l = 0; l < NLAYERS; ++l) {
        // qkv: bf16 xb -> bf16 qkv
        gemm_mfma<1, 1><<<dim3(8, 12, 32), 256, 0, stream>>>(
            xb, FEAT, (long long)TLEN * FEAT, TLEN,
            wb + qkvOff + (long long)l * 768 * FEAT, FEAT, FEAT,
            qkv, nullptr, 3 * FEAT, (long long)TLEN * 3 * FEAT,
            qkv_b + (long long)l * 3 * FEAT, nullptr, 0, nullptr, nullptr, seqlen, 1, 0);

        attn_mfma<<<dim3(4, NHEAD, NROWS), 512, 0, stream>>>(qkv, obuf, seqlen);

        // attn out: bf16 obuf -> fp32 tmp (+ residual x)
        gemm_mfma<1, 0><<<dim3(8, 4, 32), 256, 0, stream>>>(
            obuf, FEAT, (long long)TLEN * FEAT, TLEN,
            wb + aoOff + (long long)l * FEAT * FEAT, FEAT, FEAT,
            tmp, nullptr, FEAT, (long long)TLEN * FEAT,
            aob + (long long)l * FEAT, x, (long long)TLEN * FEAT, nullptr, nullptr, seqlen, 1, F_RESID);

        ln_kernel<<<dim3(126, NROWS), 256, 0, stream>>>(
            tmp, x, xb, ln1g + l * FEAT, ln1b + l * FEAT, seqlen);

        // ff1: bf16 xb -> bf16 h (GELU)
        gemm_mfma<1, 1><<<dim3(8, 16, 32), 256, 0, stream>>>(
            xb, FEAT, (long long)TLEN * FEAT, TLEN,
            wb + ff1Off + (long long)l * FFDIM * FEAT, FEAT, FEAT,
            h, nullptr, FFDIM, (long long)TLEN * FFDIM,
            ff1b + (long long)l * FFDIM, nullptr, 0, nullptr, nullptr, seqlen, 1, F_GELU);

        // ff2: bf16 h -> fp32 tmp (+ residual x)
        gemm_mfma<1, 0><<<dim3(8, 4, 32), 256, 0, stream>>>(
            h, FFDIM, (long long)TLEN * FFDIM, TLEN,
            wb + ff2Off + (long long)l * FEAT * FFDIM, FFDIM, FFDIM,
            tmp, nullptr, FEAT, (long long)TLEN * FEAT,
            ff2b + (long long)l * FEAT, x, (long long)TLEN * FEAT, nullptr, nullptr, seqlen, 1, F_RESID);

        if (l < NLAYERS - 1) {
            ln_kernel<<<dim3(126, NROWS), 256, 0, stream>>>(
                tmp, x, xb, ln2g + l * FEAT, ln2b + l * FEAT, seqlen);
        }
    }

    // fused final-LN2 + pool + projection
    pool_ln_kernel<<<NROWS, 1024, 0, stream>>>(
        tmp, ln2g + 2 * FEAT, ln2b + 2 * FEAT, outw, outb, seqlen, valid_cxr, out);
}

// Round 18
// 433.746 us; speedup vs baseline: 1.0278x; 1.0278x over previous
//
#include <hip/hip_runtime.h>
#include <math.h>

#define FEAT 256
#define NHEAD 8
#define HD 32
#define NLAYERS 3
#define EHR_IN 498
#define MAXLEN 500
#define BATCH 16
#define CXR_IN 2048
#define FFDIM 1024
#define NROWS 32
#define TLEN 501

#define F_GELU 1
#define F_RESID 2
#define F_POSEMB 4
#define F_POS0 8

typedef __bf16 bf16x8 __attribute__((ext_vector_type(8)));
typedef __bf16 bf16x4 __attribute__((ext_vector_type(4)));
typedef float f32x4 __attribute__((ext_vector_type(4)));

// ---------------------------------------------------------------------------
// Weight prep: fp32 W[K][N] -> bf16 W^T[N][Kpad] (zero-padded K).
// ---------------------------------------------------------------------------
struct WDesc { const float* src; unsigned dstOff; int K, N, Kpad; };
struct WPack { WDesc d[13]; };

__global__ __launch_bounds__(256) void wconv_kernel(WPack p, __bf16* __restrict__ wb)
{
    WDesc w = p.d[blockIdx.z];
    int n0 = blockIdx.x * 32, k0 = blockIdx.y * 32;
    if (n0 >= w.N || k0 >= w.Kpad) return;
    __shared__ float t[32][33];
    int tid = threadIdx.x;
    int c = tid & 31, r = tid >> 5;
#pragma unroll
    for (int i = 0; i < 4; ++i) {
        int k = k0 + r + i * 8;
        int n = n0 + c;
        t[r + i * 8][c] = (k < w.K && n < w.N) ? w.src[(long long)k * w.N + n] : 0.f;
    }
    __syncthreads();
    int nl = tid >> 3, kq = (tid & 7) * 4;
    int n = n0 + nl;
    if (n < w.N) {
        bf16x4 v;
#pragma unroll
        for (int j = 0; j < 4; ++j) v[j] = (__bf16)t[kq + j][nl];
        *(bf16x4*)(wb + w.dstOff + (long long)n * w.Kpad + k0 + kq) = v;
    }
}

// ---------------------------------------------------------------------------
// bf16 MFMA GEMM, BK=64, double-buffered LDS (validated r12: 445 us).
// Padded LDS rows (72 bf16 = 144 B) keep bank spread; do NOT replace with
// unpadded+XOR (r15 lesson: 16B-chunk swizzle can't fix stride%128B==0).
// ABF: 1 = A bf16, 0 = A fp32. CBF: 0 fp32 / 1 bf16 / 2 both.
// ---------------------------------------------------------------------------
template<int ABF, int CBF>
__global__ __launch_bounds__(256) void gemm_mfma(
    const void* __restrict__ Av, int lda, long long aStrideZ, int Mrows,
    const __bf16* __restrict__ WT, int kpad, int K,
    void* __restrict__ Cv, void* __restrict__ Cv2, int ldc, long long cStrideZ,
    const float* __restrict__ bias,
    const float* __restrict__ resid, long long resStrideZ,
    const float* __restrict__ modv, const float* __restrict__ posm,
    const int* __restrict__ seqlen, int lenMode, int flags)
{
    int z = blockIdx.z;
    int len = (lenMode == 2) ? Mrows
            : (lenMode == 0) ? seqlen[z]
            : ((z & 1) ? 1 : seqlen[z >> 1]);
    int m0 = blockIdx.x * 64;
    if (m0 >= len) return;
    int n0 = blockIdx.y * 64;

    __shared__ __bf16 As[2][64][72];
    __shared__ __bf16 Bs[2][64][72];

    int tid = threadIdx.x;
    int wave = tid >> 6, lane = tid & 63;
    int wm = wave >> 1, wn = wave & 1;
    int fm = lane & 15, kgrp = lane >> 4;

    f32x4 acc[2][2];
#pragma unroll
    for (int i = 0; i < 2; ++i)
#pragma unroll
        for (int j = 0; j < 2; ++j)
#pragma unroll
            for (int r = 0; r < 4; ++r) acc[i][j][r] = 0.f;

    int srow = tid >> 2;          // 0..63
    int skq  = (tid & 3) * 16;    // 0/16/32/48
    int garow = m0 + srow;
    bool rowok = garow < Mrows;

    int nk = (K + 63) >> 6;
    bf16x8 a0, a1, b0, b1;

    auto loadAB = [&](int kt) {
        int k0 = kt << 6;
        if (ABF) {
            if (rowok) {
                const __bf16* ap = (const __bf16*)Av + (long long)z * aStrideZ
                                 + (long long)garow * lda + k0 + skq;
                a0 = *(const bf16x8*)ap;
                a1 = *(const bf16x8*)(ap + 8);
            } else {
#pragma unroll
                for (int j = 0; j < 8; ++j) { a0[j] = (__bf16)0.f; a1[j] = (__bf16)0.f; }
            }
        } else {
            const float* ap = (const float*)Av + (long long)z * aStrideZ
                            + (long long)garow * lda + k0 + skq;
            float va[16];
            if (rowok && k0 + skq + 15 < K) {
#pragma unroll
                for (int j = 0; j < 16; j += 2) {
                    float2 t = *(const float2*)(ap + j);
                    va[j] = t.x; va[j + 1] = t.y;
                }
            } else {
#pragma unroll
                for (int j = 0; j < 16; ++j)
                    va[j] = (rowok && k0 + skq + j < K) ? ap[j] : 0.f;
            }
#pragma unroll
            for (int j = 0; j < 8; ++j) {
                a0[j] = (__bf16)va[j];
                a1[j] = (__bf16)va[j + 8];
            }
        }
        const __bf16* wp = WT + (long long)(n0 + srow) * kpad + k0 + skq;
        b0 = *(const bf16x8*)wp;
        b1 = *(const bf16x8*)(wp + 8);
    };

    auto writeAB = [&](int buf) {
        *(bf16x8*)&As[buf][srow][skq]     = a0;
        *(bf16x8*)&As[buf][srow][skq + 8] = a1;
        *(bf16x8*)&Bs[buf][srow][skq]     = b0;
        *(bf16x8*)&Bs[buf][srow][skq + 8] = b1;
    };

    loadAB(0);
    writeAB(0);
    __syncthreads();

    for (int kt = 0; kt < nk; ++kt) {
        int cur = kt & 1;
        bool more = (kt + 1 < nk);
        if (more) loadAB(kt + 1);    // global loads in flight during MFMAs
#pragma unroll
        for (int kk2 = 0; kk2 < 2; ++kk2) {
            bf16x8 bfr[2];
#pragma unroll
            for (int j = 0; j < 2; ++j)
                bfr[j] = *(const bf16x8*)&Bs[cur][wn * 32 + j * 16 + fm][kk2 * 32 + kgrp * 8];
#pragma unroll
            for (int i = 0; i < 2; ++i) {
                bf16x8 af = *(const bf16x8*)&As[cur][wm * 32 + i * 16 + fm][kk2 * 32 + kgrp * 8];
#pragma unroll
                for (int j = 0; j < 2; ++j)
                    acc[i][j] = __builtin_amdgcn_mfma_f32_16x16x32_bf16(af, bfr[j], acc[i][j], 0, 0, 0);
            }
        }
        if (more) writeAB(cur ^ 1);
        __syncthreads();
    }

    int rbase = (lane >> 4) * 4;
    int ccol = lane & 15;
#pragma unroll
    for (int i = 0; i < 2; ++i) {
#pragma unroll
        for (int r = 0; r < 4; ++r) {
            int gm = m0 + wm * 32 + i * 16 + rbase + r;
            if (gm >= len) continue;
#pragma unroll
            for (int j = 0; j < 2; ++j) {
                int gn = n0 + wn * 32 + j * 16 + ccol;
                float v = acc[i][j][r] + bias[gn];
                if (flags & F_POSEMB) v += modv[gn] + posm[(long long)gm * FEAT + gn];
                if (flags & F_POS0)   v += modv[gn] + posm[gn];
                if (flags & F_RESID)  v += resid[(long long)z * resStrideZ + (long long)gm * ldc + gn];
                if (flags & F_GELU)   v = 0.5f * v * (1.f + erff(v * 0.70710678118654752f));
                long long cidx = (long long)z * cStrideZ + (long long)gm * ldc + gn;
                if (CBF == 1) ((__bf16*)Cv)[cidx] = (__bf16)v;
                else          ((float*)Cv)[cidx] = v;
                if (CBF == 2) ((__bf16*)Cv2)[cidx] = (__bf16)v;
            }
        }
    }
}

// ---------------------------------------------------------------------------
// CXR projection, K-split 2-pass fp32 (validated round 7).
// ---------------------------------------------------------------------------
__global__ __launch_bounds__(256) void cxr_part(
    const float* __restrict__ cxr, const float* __restrict__ W,
    float* __restrict__ part)
{
    int b = blockIdx.x, ks = blockIdx.y;
    int n = threadIdx.x;
    __shared__ float a[128];
    int k0 = ks * 128;
    if (n < 128) a[n] = cxr[(long long)b * CXR_IN + k0 + n];
    __syncthreads();
    float acc0 = 0.f, acc1 = 0.f, acc2 = 0.f, acc3 = 0.f;
    const float* wp = W + (long long)k0 * FEAT + n;
#pragma unroll 8
    for (int k = 0; k < 128; k += 4) {
        acc0 += a[k]     * wp[(long long)k * FEAT];
        acc1 += a[k + 1] * wp[(long long)(k + 1) * FEAT];
        acc2 += a[k + 2] * wp[(long long)(k + 2) * FEAT];
        acc3 += a[k + 3] * wp[(long long)(k + 3) * FEAT];
    }
    part[((long long)b * 16 + ks) * FEAT + n] = acc0 + acc1 + acc2 + acc3;
}

__global__ __launch_bounds__(256) void cxr_fin(
    const float* __restrict__ part, const float* __restrict__ bias,
    const float* __restrict__ mod1, const float* __restrict__ pos0,
    float* __restrict__ x, __bf16* __restrict__ xb)
{
    int b = blockIdx.x;
    int n = threadIdx.x;
    float s = 0.f;
#pragma unroll
    for (int ks = 0; ks < 16; ++ks)
        s += part[((long long)b * 16 + ks) * FEAT + n];
    float v = s + bias[n] + mod1[n] + pos0[n];
    long long idx = ((long long)(2 * b + 1) * TLEN) * FEAT + n;
    x[idx] = v;
    xb[idx] = (__bf16)v;
}

// ---------------------------------------------------------------------------
// MFMA flash attention, q-tile 128, 8 waves (512 threads); validated r11.
// ---------------------------------------------------------------------------
__global__ __launch_bounds__(512) void attn_mfma(
    const __bf16* __restrict__ qkv, __bf16* __restrict__ o,
    const int* __restrict__ seqlen)
{
    int n = blockIdx.z, h = blockIdx.y, qt = blockIdx.x;
    int len = (n & 1) ? 1 : seqlen[n >> 1];
    int q0 = qt * 128;
    if (q0 >= len) return;

    int tid = threadIdx.x;
    int wave = tid >> 6, lane = tid & 63;
    int fr = lane & 15, kg = lane >> 4;

    const __bf16* base = qkv + (long long)n * TLEN * 768;
    const float scale = 0.17677669529663687f;

    int qrow = q0 + wave * 16 + fr;
    if (qrow >= len) qrow = len - 1;
    bf16x8 qfrag = *(const bf16x8*)(base + (long long)qrow * 768 + h * HD + kg * 8);

    f32x4 po0 = {0.f, 0.f, 0.f, 0.f}, po1 = {0.f, 0.f, 0.f, 0.f};
    float m = -3.0e38f, l = 0.f;

    __shared__ bf16x8 stage[2][544];

    int t2 = tid & 255;
    int f_    = t2 >> 6;
    int kgrp_ = (t2 >> 4) & 3;
    int mm_   = t2 & 15;
    int kKeyL  = ((mm_ >> 2) << 3) + ((f_ & 1) << 2) + (mm_ & 3) + ((f_ >> 1) << 5);
    int kChunk = (f_ * 4 + kgrp_) * 17 + mm_;
    int vDim   = ((f_ & 1) << 4) + mm_;
    int vKeyB  = ((f_ >> 1) << 5) + (kgrp_ << 3);
    int vChunk = 272 + (f_ * 4 + kgrp_) * 17 + mm_;

    int nt = (len + 63) >> 6;

    auto do_stage = [&](int t, int buf) {
        int k0 = t << 6;
        if (tid < 256) {
            bf16x8 kv;
            int key = k0 + kKeyL;
            if (key < len) {
                kv = *(const bf16x8*)(base + (long long)key * 768 + 256 + h * HD + kgrp_ * 8);
            } else {
#pragma unroll
                for (int j = 0; j < 8; ++j) kv[j] = (__bf16)0.f;
            }
            stage[buf][kChunk] = kv;
        } else {
            bf16x8 vv;
#pragma unroll
            for (int j = 0; j < 8; ++j) {
                int vkey = k0 + vKeyB + j;
                vv[j] = (vkey < len) ? base[(long long)vkey * 768 + 512 + h * HD + vDim]
                                     : (__bf16)0.f;
            }
            stage[buf][vChunk] = vv;
        }
    };

    do_stage(0, 0);
    __syncthreads();

    for (int t = 0; t < nt; ++t) {
        int buf = t & 1;
        if (t + 1 < nt) do_stage(t + 1, buf ^ 1);

        int k0 = t << 6;
        bf16x8 kf0 = stage[buf][(0 * 4 + kg) * 17 + fr];
        bf16x8 kf1 = stage[buf][(1 * 4 + kg) * 17 + fr];
        bf16x8 kf2 = stage[buf][(2 * 4 + kg) * 17 + fr];
        bf16x8 kf3 = stage[buf][(3 * 4 + kg) * 17 + fr];

        f32x4 zero = {0.f, 0.f, 0.f, 0.f};
        f32x4 s0 = __builtin_amdgcn_mfma_f32_16x16x32_bf16(kf0, qfrag, zero, 0, 0, 0);
        f32x4 s1 = __builtin_amdgcn_mfma_f32_16x16x32_bf16(kf1, qfrag, zero, 0, 0, 0);
        f32x4 s2 = __builtin_amdgcn_mfma_f32_16x16x32_bf16(kf2, qfrag, zero, 0, 0, 0);
        f32x4 s3 = __builtin_amdgcn_mfma_f32_16x16x32_bf16(kf3, qfrag, zero, 0, 0, 0);

        float sc[16];
        int kb = k0 + kg * 8;
#pragma unroll
        for (int r = 0; r < 4; ++r) {
            sc[r]      = (kb + r < len)      ? s0[r] * scale : -3.0e38f;
            sc[4 + r]  = (kb + 4 + r < len)  ? s1[r] * scale : -3.0e38f;
            sc[8 + r]  = (kb + 32 + r < len) ? s2[r] * scale : -3.0e38f;
            sc[12 + r] = (kb + 36 + r < len) ? s3[r] * scale : -3.0e38f;
        }
        float tm = sc[0];
#pragma unroll
        for (int i = 1; i < 16; ++i) tm = fmaxf(tm, sc[i]);
        tm = fmaxf(tm, __shfl_xor(tm, 16));
        tm = fmaxf(tm, __shfl_xor(tm, 32));
        float mn = fmaxf(m, tm);
        float corr = __expf(m - mn);
        l *= corr;
#pragma unroll
        for (int r = 0; r < 4; ++r) { po0[r] *= corr; po1[r] *= corr; }
        m = mn;

        float p[16];
        float lsum = 0.f;
#pragma unroll
        for (int i = 0; i < 16; ++i) { p[i] = __expf(sc[i] - m); lsum += p[i]; }
        lsum += __shfl_xor(lsum, 16);
        lsum += __shfl_xor(lsum, 32);
        l += lsum;

        bf16x8 pf0, pf1;
#pragma unroll
        for (int j = 0; j < 8; ++j) { pf0[j] = (__bf16)p[j]; pf1[j] = (__bf16)p[8 + j]; }

        bf16x8 vf00 = stage[buf][272 + (0 * 4 + kg) * 17 + fr];
        bf16x8 vf01 = stage[buf][272 + (1 * 4 + kg) * 17 + fr];
        bf16x8 vf10 = stage[buf][272 + (2 * 4 + kg) * 17 + fr];
        bf16x8 vf11 = stage[buf][272 + (3 * 4 + kg) * 17 + fr];

        po0 = __builtin_amdgcn_mfma_f32_16x16x32_bf16(vf00, pf0, po0, 0, 0, 0);
        po0 = __builtin_amdgcn_mfma_f32_16x16x32_bf16(vf10, pf1, po0, 0, 0, 0);
        po1 = __builtin_amdgcn_mfma_f32_16x16x32_bf16(vf01, pf0, po1, 0, 0, 0);
        po1 = __builtin_amdgcn_mfma_f32_16x16x32_bf16(vf11, pf1, po1, 0, 0, 0);

        __syncthreads();
    }

    int q = q0 + wave * 16 + fr;
    if (q < len) {
        float inv = 1.f / l;
        __bf16* orow = o + ((long long)n * TLEN + q) * FEAT + h * HD;
        bf16x4 w0, w1;
#pragma unroll
        for (int r = 0; r < 4; ++r) {
            w0[r] = (__bf16)(po0[r] * inv);
            w1[r] = (__bf16)(po1[r] * inv);
        }
        *(bf16x4*)(orow + kg * 4) = w0;
        *(bf16x4*)(orow + 16 + kg * 4) = w1;
    }
}

// ---------------------------------------------------------------------------
// LayerNorm over last dim (256). 256-thread blocks = 4 waves, one wave per
// row. Writes fp32 x AND bf16 xb. (Validated r16.)
// ---------------------------------------------------------------------------
__global__ __launch_bounds__(256) void ln_kernel(
    const float* __restrict__ tmp, float* __restrict__ x, __bf16* __restrict__ xb,
    const float* __restrict__ g, const float* __restrict__ b,
    const int* __restrict__ seqlen)
{
    int n = blockIdx.y;
    int len = (n & 1) ? 1 : seqlen[n >> 1];
    int t = blockIdx.x * 4 + (threadIdx.x >> 6);
    if (t >= len) return;
    int tid = threadIdx.x & 63;
    const float* row = tmp + ((long long)n * TLEN + t) * FEAT;
    int f = tid * 4;
    float4 v = *(const float4*)(row + f);
    float s = v.x + v.y + v.z + v.w;
#pragma unroll
    for (int off = 32; off; off >>= 1) s += __shfl_down(s, off);
    float mu = __shfl(s, 0) * (1.f / 256.f);
    float dx = v.x - mu, dy = v.y - mu, dz = v.z - mu, dw = v.w - mu;
    float q = dx * dx + dy * dy + dz * dz + dw * dw;
#pragma unroll
    for (int off = 32; off; off >>= 1) q += __shfl_down(q, off);
    float var = __shfl(q, 0) * (1.f / 256.f);
    float r = rsqrtf(var + 1e-5f);
    float4 ov;
    ov.x = dx * r * g[f + 0] + b[f + 0];
    ov.y = dy * r * g[f + 1] + b[f + 1];
    ov.z = dz * r * g[f + 2] + b[f + 2];
    ov.w = dw * r * g[f + 3] + b[f + 3];
    long long idx = ((long long)n * TLEN + t) * FEAT + f;
    *(float4*)(x + idx) = ov;
    bf16x4 bv;
    bv[0] = (__bf16)ov.x; bv[1] = (__bf16)ov.y;
    bv[2] = (__bf16)ov.z; bv[3] = (__bf16)ov.w;
    *(bf16x4*)(xb + idx) = bv;
}

// ---------------------------------------------------------------------------
// Masked mean-pool + output projection (x2 outputs). valid_cxr is int32.
// ---------------------------------------------------------------------------
__global__ __launch_bounds__(1024) void pool_out_kernel(
    const float* __restrict__ x, const float* __restrict__ W,
    const float* __restrict__ b, const int* __restrict__ seqlen,
    const int* __restrict__ valid_cxr, float* __restrict__ out)
{
    int n = blockIdx.x;
    int tid = threadIdx.x;
    int f = tid & 255;
    int tg = tid >> 8;
    int cnt = (n & 1) ? (valid_cxr[n >> 1] != 0 ? 1 : 0) : seqlen[n >> 1];

    __shared__ float part[4][FEAT];
    __shared__ float pooled[FEAT];

    const float* xb = x + (long long)n * TLEN * FEAT + f;
    float s0 = 0.f, s1 = 0.f;
    int t = tg;
    for (; t + 4 < cnt; t += 8) {
        s0 += xb[(long long)t * FEAT];
        s1 += xb[(long long)(t + 4) * FEAT];
    }
    if (t < cnt) s0 += xb[(long long)t * FEAT];
    part[tg][f] = s0 + s1;
    __syncthreads();
    if (tg == 0) {
        float v = part[0][f] + part[1][f] + part[2][f] + part[3][f];
        pooled[f] = cnt ? v / (float)cnt : 0.f;
    }
    __syncthreads();

    float acc = 0.f;
    const float* wcol = W + f;
#pragma unroll 8
    for (int k = tg * 64; k < tg * 64 + 64; ++k)
        acc += pooled[k] * wcol[(long long)k * FEAT];
    __syncthreads();
    part[tg][f] = acc;
    __syncthreads();
    if (tg == 0) {
        float v = part[0][f] + part[1][f] + part[2][f] + part[3][f] + b[f];
        out[(long long)n * FEAT + f] = v;
        out[NROWS * FEAT + (long long)n * FEAT + f] = v;
    }
}

// ---------------------------------------------------------------------------
extern "C" void kernel_launch(void* const* d_in, const int* in_sizes, int n_in,
                              void* d_out, int out_size, void* d_ws, size_t ws_size,
                              hipStream_t stream)
{
    const float* ehr_data = (const float*)d_in[0];
    const float* cxr_data = (const float*)d_in[1];
    const int*   seqlen   = (const int*)d_in[2];
    const int*   valid_cxr = (const int*)d_in[3];
    const float* ehr_w = (const float*)d_in[4];
    const float* ehr_b = (const float*)d_in[5];
    const float* cxr_w = (const float*)d_in[6];
    const float* cxr_b = (const float*)d_in[7];
    const float* modemb = (const float*)d_in[8];
    const float* pos    = (const float*)d_in[9];
    const float* qkv_w  = (const float*)d_in[10];
    const float* qkv_b  = (const float*)d_in[11];
    const float* aow    = (const float*)d_in[12];
    const float* aob    = (const float*)d_in[13];
    const float* ln1g   = (const float*)d_in[14];
    const float* ln1b   = (const float*)d_in[15];
    const float* ln2g   = (const float*)d_in[16];
    const float* ln2b   = (const float*)d_in[17];
    const float* ff1w   = (const float*)d_in[18];
    const float* ff1b   = (const float*)d_in[19];
    const float* ff2w   = (const float*)d_in[20];
    const float* ff2b   = (const float*)d_in[21];
    const float* outw   = (const float*)d_in[22];
    const float* outb   = (const float*)d_in[23];
    float* out = (float*)d_out;

    // ---- workspace layout (float slots) ----
    float* ws    = (float*)d_ws;
    float* x     = ws;
    __bf16* xb   = (__bf16*)(ws + 4104192);
    __bf16* qkv  = (__bf16*)(ws + 6156288);
    __bf16* obuf = (__bf16*)(ws + 12312576);
    __bf16* h    = (__bf16*)(ws + 6156288);
    float* tmp   = ws + 14364672;
    __bf16* wb   = (__bf16*)(ws + 18468864);
    float* cpart = ws + 19714048;

    WPack p;
    unsigned off = 0;
    p.d[0] = { ehr_w, off, EHR_IN, FEAT, 512 };            off += 256 * 512;
    unsigned qkvOff = off;
    for (int l = 0; l < 3; ++l) { p.d[1 + l] = { qkv_w + (long long)l * FEAT * 768, off, FEAT, 768, FEAT };  off += 768 * FEAT; }
    unsigned aoOff = off;
    for (int l = 0; l < 3; ++l) { p.d[4 + l] = { aow + (long long)l * FEAT * FEAT, off, FEAT, FEAT, FEAT };  off += FEAT * FEAT; }
    unsigned ff1Off = off;
    for (int l = 0; l < 3; ++l) { p.d[7 + l] = { ff1w + (long long)l * FEAT * FFDIM, off, FEAT, FFDIM, FEAT }; off += FFDIM * FEAT; }
    unsigned ff2Off = off;
    for (int l = 0; l < 3; ++l) { p.d[10 + l] = { ff2w + (long long)l * FFDIM * FEAT, off, FFDIM, FEAT, FFDIM }; off += FEAT * FFDIM; }

    wconv_kernel<<<dim3(32, 32, 13), 256, 0, stream>>>(p, wb);

    // ehr projection -> even rows of x (+ bf16 mirror xb)
    gemm_mfma<0, 2><<<dim3(8, 4, 16), 256, 0, stream>>>(
        ehr_data, EHR_IN, (long long)MAXLEN * EHR_IN, MAXLEN,
        wb + 0, 512, EHR_IN,
        x, xb, FEAT, (long long)2 * TLEN * FEAT,
        ehr_b, nullptr, 0, modemb, pos, seqlen, 0, F_POSEMB);
    // cxr projection -> odd rows token 0 (+ xb)
    cxr_part<<<dim3(BATCH, 16), 256, 0, stream>>>(cxr_data, cxr_w, cpart);
    cxr_fin<<<BATCH, 256, 0, stream>>>(cpart, cxr_b, modemb + FEAT, pos, x, xb);

    for (int l = 0; l < NLAYERS; ++l) {
        // qkv: bf16 xb -> bf16 qkv
        gemm_mfma<1, 1><<<dim3(8, 12, 32), 256, 0, stream>>>(
            xb, FEAT, (long long)TLEN * FEAT, TLEN,
            wb + qkvOff + (long long)l * 768 * FEAT, FEAT, FEAT,
            qkv, nullptr, 3 * FEAT, (long long)TLEN * 3 * FEAT,
            qkv_b + (long long)l * 3 * FEAT, nullptr, 0, nullptr, nullptr, seqlen, 1, 0);

        attn_mfma<<<dim3(4, NHEAD, NROWS), 512, 0, stream>>>(qkv, obuf, seqlen);

        // attn out: bf16 obuf -> fp32 tmp (+ residual x)
        gemm_mfma<1, 0><<<dim3(8, 4, 32), 256, 0, stream>>>(
            obuf, FEAT, (long long)TLEN * FEAT, TLEN,
            wb + aoOff + (long long)l * FEAT * FEAT, FEAT, FEAT,
            tmp, nullptr, FEAT, (long long)TLEN * FEAT,
            aob + (long long)l * FEAT, x, (long long)TLEN * FEAT, nullptr, nullptr, seqlen, 1, F_RESID);

        ln_kernel<<<dim3(126, NROWS), 256, 0, stream>>>(
            tmp, x, xb, ln1g + l * FEAT, ln1b + l * FEAT, seqlen);

        // ff1: bf16 xb -> bf16 h (GELU)
        gemm_mfma<1, 1><<<dim3(8, 16, 32), 256, 0, stream>>>(
            xb, FEAT, (long long)TLEN * FEAT, TLEN,
            wb + ff1Off + (long long)l * FFDIM * FEAT, FEAT, FEAT,
            h, nullptr, FFDIM, (long long)TLEN * FFDIM,
            ff1b + (long long)l * FFDIM, nullptr, 0, nullptr, nullptr, seqlen, 1, F_GELU);

        // ff2: bf16 h -> fp32 tmp (+ residual x)
        gemm_mfma<1, 0><<<dim3(8, 4, 32), 256, 0, stream>>>(
            h, FFDIM, (long long)TLEN * FFDIM, TLEN,
            wb + ff2Off + (long long)l * FEAT * FFDIM, FFDIM, FFDIM,
            tmp, nullptr, FEAT, (long long)TLEN * FEAT,
            ff2b + (long long)l * FEAT, x, (long long)TLEN * FEAT, nullptr, nullptr, seqlen, 1, F_RESID);

        ln_kernel<<<dim3(126, NROWS), 256, 0, stream>>>(
            tmp, x, xb, ln2g + l * FEAT, ln2b + l * FEAT, seqlen);
    }

    pool_out_kernel<<<NROWS, 1024, 0, stream>>>(x, outw, outb, seqlen, valid_cxr, out);
}